// Round 10
// baseline (266.057 us; speedup 1.0000x reference)
//
#include <hip/hip_runtime.h>

#define NG 16
#define NC 4
#define BPB 8      // batch items per block
#define TSTEPS 8
#define PITCH 34   // float4 per (c,y) row: 16 x * 2 quad-slots + 2 pad
#define CROW (NG * PITCH)   // 544 float4 per channel

__device__ __forceinline__ void fma4(float w, const float4& s, float4& a) {
    a.x = fmaf(w, s.x, a.x);
    a.y = fmaf(w, s.y, a.y);
    a.z = fmaf(w, s.z, a.z);
    a.w = fmaf(w, s.w, a.w);
}

__device__ __forceinline__ float4 lrelu4(float4 v) {
    float4 r;
    r.x = fmaxf(v.x, 0.1f * v.x);
    r.y = fmaxf(v.y, 0.1f * v.y);
    r.z = fmaxf(v.z, 0.1f * v.z);
    r.w = fmaxf(v.w, 0.1f * v.w);
    return r;
}

// DPP row shift within 16-lane rows; bound_ctrl=1 zero-fills at row edges
// (matches reference zero padding; OOB weights are pre-zeroed anyway).
// 0x111/0x112 = row_shr:1/2 (tap x-1/x-2); 0x101/0x102 = row_shl:1/2 (x+1/x+2).
template<int CTRL>
__device__ __forceinline__ float dppf(float x) {
    return __int_as_float(__builtin_amdgcn_update_dpp(
        0, __float_as_int(x), CTRL, 0xF, 0xF, true));
}
template<int CTRL>
__device__ __forceinline__ float4 dpp4(float4 v) {
    float4 r;
    r.x = dppf<CTRL>(v.x);
    r.y = dppf<CTRL>(v.y);
    r.z = dppf<CTRL>(v.z);
    r.w = dppf<CTRL>(v.w);
    return r;
}

// Wt[(c*25+u*5+v)*256 + pix] : float4 over o, OOB (u,v) pre-zeroed.
// Original W: [y][x][o][c][u][v] (flat: pix*400 + o*100 + c*25 + u*5 + v)
__global__ void wt_transpose(const float* __restrict__ W, float4* __restrict__ Wt) {
    int t = blockIdx.x * 256 + threadIdx.x;   // 0..25599
    if (t >= 25600) return;
    int r = t >> 8;            // c*25 + u*5 + v
    int pix = t & 255;
    int c = r / 25, uv = r - c * 25, u = uv / 5, v = uv - u * 5;
    int y = pix >> 4, x = pix & 15;
    float4 w = make_float4(0.f, 0.f, 0.f, 0.f);
    if ((unsigned)(y + u - 2) < 16u && (unsigned)(x + v - 2) < 16u) {
        int base = pix * 400 + c * 25 + uv;
        w.x = W[base];
        w.y = W[base + 100];
        w.z = W[base + 200];
        w.w = W[base + 300];
    }
    Wt[r * 256 + pix] = w;
}

// 512 threads = 2 batch-quads x 256 pixels (tid = quad*256 + pix), so each
// wave is 64 consecutive pixels of one quad -> R9's DPP geometry unchanged.
// Each thread: 4 o-channels x 4 batch items (acc 16 VGPR), own-pixel state =
// 1 float4 per (c,u) chunk (1 ds_read_b128), weights single-buffered
// (5 float4 = 20 VGPR) streamed chunk-by-chunk in a RUNTIME c/u loop (fences
// scheduler load-hoisting). True pressure ~60 VGPR -> fits the 64-VGPR /
// 8-waves-per-SIMD budget with ZERO spill (R8/R9 spilled at this cap).
// LDS 34816 B -> 4 blocks/CU -> 32 waves/CU. Single-buffer load latency is
// hidden by 8-wave TLP (per-SIMD VALU demand >> per-wave stall).
__global__ __launch_bounds__(512, 8)
void reservoir_kernel(const float* __restrict__ X, const float4* __restrict__ Wt,
                      float* __restrict__ out, int batch) {
    __shared__ float4 smv[NC * CROW];   // 34816 B
    float* smf = reinterpret_cast<float*>(smv);

    const int tid = threadIdx.x;
    const int bh  = tid >> 8;          // batch quad (0: items 0-3, 1: items 4-7)
    const int pix = tid & 255;
    const int y = pix >> 4;
    const int x = pix & 15;
    const long itemBase = (long)blockIdx.x * BPB;

    // ---- init: X (first 784 of 1024 slots) -> LDS ----
    for (int b = 0; b < BPB; ++b) {
        long item = itemBase + b;
        #pragma unroll
        for (int k = 0; k < 2; ++k) {
            int idx = tid + k * 512;    // 0..1023
            float v = 0.f;
            if (idx < 784 && item < batch)
                v = __builtin_nontemporal_load(&X[item * 784 + idx]);
            int c = idx >> 8, rem = idx & 255, yy = rem >> 4, xx = rem & 15;
            int phys = (b >> 2) ^ ((xx >> 2) & 1);
            smf[((c * NG + yy) * PITCH + xx * 2 + phys) * 4 + (b & 3)] = v;
        }
    }

    const int swx = (x >> 2) & 1;
    const int xq  = x * 2 + (bh ^ swx);   // own pixel+quad f4 offset in a row

    // ---- weights: single-buffered 5 x float4, chunk 0 preloaded ----
    const float4* Wp = Wt + pix;
    float4 w0 = Wp[0], w1 = Wp[256], w2 = Wp[512], w3 = Wp[768], w4 = Wp[1024];
    int wnext = 1280;    // f4 offset of next chunk to load (chunk k at k*1280)

    __syncthreads();

    #pragma unroll 1
    for (int t = 0; t < TSTEPS; ++t) {
        float4 a0 = {0,0,0,0}, a1 = {0,0,0,0}, a2 = {0,0,0,0}, a3 = {0,0,0,0};

        #pragma unroll 1
        for (int c = 0; c < NC; ++c) {
            const int cb = c * CROW;
            #pragma unroll 1
            for (int u = 0; u < 5; ++u) {
                int yy = y + u - 2;
                yy = yy < 0 ? 0 : (yy > 15 ? 15 : yy);   // OOB rows: w pre-zeroed
                const float4 s = smv[cb + yy * PITCH + xq];

                // v=2 (center)
                fma4(w2.x, s, a0); fma4(w2.y, s, a1);
                fma4(w2.z, s, a2); fma4(w2.w, s, a3);
                { const float4 tp = dpp4<0x111>(s);   // x-1 -> v=1
                  fma4(w1.x, tp, a0); fma4(w1.y, tp, a1);
                  fma4(w1.z, tp, a2); fma4(w1.w, tp, a3); }
                { const float4 tp = dpp4<0x101>(s);   // x+1 -> v=3
                  fma4(w3.x, tp, a0); fma4(w3.y, tp, a1);
                  fma4(w3.z, tp, a2); fma4(w3.w, tp, a3); }
                { const float4 tp = dpp4<0x112>(s);   // x-2 -> v=0
                  fma4(w0.x, tp, a0); fma4(w0.y, tp, a1);
                  fma4(w0.z, tp, a2); fma4(w0.w, tp, a3); }
                { const float4 tp = dpp4<0x102>(s);   // x+2 -> v=4
                  fma4(w4.x, tp, a0); fma4(w4.y, tp, a1);
                  fma4(w4.z, tp, a2); fma4(w4.w, tp, a3); }

                // reload same regs with the NEXT chunk (after all consumers)
                __builtin_amdgcn_sched_barrier(0);
                w0 = Wp[wnext];
                w1 = Wp[wnext + 256];
                w2 = Wp[wnext + 512];
                w3 = Wp[wnext + 768];
                w4 = Wp[wnext + 1024];
                wnext += 1280;
                if (wnext >= 25600) wnext = 0;   // chunk 19 reloads chunk 0
            }
        }

        a0 = lrelu4(a0); a1 = lrelu4(a1); a2 = lrelu4(a2); a3 = lrelu4(a3);

        if (t < TSTEPS - 1) {
            __syncthreads();   // all reads of S[t] complete before overwrite
            const int pa = y * PITCH + x * 2 + (bh ^ swx);
            smv[0 * CROW + pa] = a0;
            smv[1 * CROW + pa] = a1;
            smv[2 * CROW + pa] = a2;
            smv[3 * CROW + pa] = a3;
            __syncthreads();   // writes visible before next read phase
        } else {
            // channel-mean for this thread's 4 batch items
            float4 p;
            p.x = (a0.x + a1.x + a2.x + a3.x) * 0.25f;
            p.y = (a0.y + a1.y + a2.y + a3.y) * 0.25f;
            p.z = (a0.z + a1.z + a2.z + a3.z) * 0.25f;
            p.w = (a0.w + a1.w + a2.w + a3.w) * 0.25f;
            const long b0 = itemBase + bh * 4;
            const long ob = b0 * 256 + pix;
            if (b0 + 0 < batch) __builtin_nontemporal_store(p.x, &out[ob + 0 * 256]);
            if (b0 + 1 < batch) __builtin_nontemporal_store(p.y, &out[ob + 1 * 256]);
            if (b0 + 2 < batch) __builtin_nontemporal_store(p.z, &out[ob + 2 * 256]);
            if (b0 + 3 < batch) __builtin_nontemporal_store(p.w, &out[ob + 3 * 256]);
        }
    }
}

extern "C" void kernel_launch(void* const* d_in, const int* in_sizes, int n_in,
                              void* d_out, int out_size, void* d_ws, size_t ws_size,
                              hipStream_t stream) {
    const float* X = (const float*)d_in[0];
    const float* W = (const float*)d_in[1];
    float* out = (float*)d_out;
    const int batch = in_sizes[0] / 784;            // 8192
    const int blocks = (batch + BPB - 1) / BPB;     // 1024

    wt_transpose<<<100, 256, 0, stream>>>(W, (float4*)d_ws);
    reservoir_kernel<<<blocks, 512, 0, stream>>>(
        X, (const float4*)d_ws, out, batch);
}

// Round 11
// 214.075 us; speedup vs baseline: 1.2428x; 1.2428x over previous
//
#include <hip/hip_runtime.h>

#define NG 16
#define NC 4
#define BPB 16     // batch items per block (= per thread)
#define TSTEPS 8
#define PITCH 64   // float4 per (c,y) row: 16 x * 4 quad-slots (swizzled)
#define CROW (NG * PITCH)   // 1024 float4 per channel

__device__ __forceinline__ void fma4(float w, const float4& s, float4& a) {
    a.x = fmaf(w, s.x, a.x);
    a.y = fmaf(w, s.y, a.y);
    a.z = fmaf(w, s.z, a.z);
    a.w = fmaf(w, s.w, a.w);
}

__device__ __forceinline__ float4 lrelu4(float4 v) {
    float4 r;
    r.x = fmaxf(v.x, 0.1f * v.x);
    r.y = fmaxf(v.y, 0.1f * v.y);
    r.z = fmaxf(v.z, 0.1f * v.z);
    r.w = fmaxf(v.w, 0.1f * v.w);
    return r;
}

// DPP row shift within 16-lane rows; bound_ctrl=1 zero-fills at row edges
// (matches reference zero padding; OOB weights pre-zeroed anyway).
// 0x111/0x112 = row_shr:1/2 (tap x-1/x-2); 0x101/0x102 = row_shl:1/2 (x+1/x+2).
template<int CTRL>
__device__ __forceinline__ float dppf(float x) {
    return __int_as_float(__builtin_amdgcn_update_dpp(
        0, __float_as_int(x), CTRL, 0xF, 0xF, true));
}
template<int CTRL>
__device__ __forceinline__ float4 dpp4(float4 v) {
    float4 r;
    r.x = dppf<CTRL>(v.x);
    r.y = dppf<CTRL>(v.y);
    r.z = dppf<CTRL>(v.z);
    r.w = dppf<CTRL>(v.w);
    return r;
}

// Wt[(c*25+u*5+v)*256 + pix] : float4 over o, OOB (u,v) pre-zeroed.
// Original W: [y][x][o][c][u][v] (flat: pix*400 + o*100 + c*25 + u*5 + v)
__global__ void wt_transpose(const float* __restrict__ W, float4* __restrict__ Wt) {
    int t = blockIdx.x * 256 + threadIdx.x;   // 0..25599
    if (t >= 25600) return;
    int r = t >> 8;            // c*25 + u*5 + v
    int pix = t & 255;
    int c = r / 25, uv = r - c * 25, u = uv / 5, v = uv - u * 5;
    int y = pix >> 4, x = pix & 15;
    float4 w = make_float4(0.f, 0.f, 0.f, 0.f);
    if ((unsigned)(y + u - 2) < 16u && (unsigned)(x + v - 2) < 16u) {
        int base = pix * 400 + c * 25 + uv;
        w.x = W[base];
        w.y = W[base + 100];
        w.z = W[base + 200];
        w.w = W[base + 300];
    }
    Wt[r * 256 + pix] = w;
}

// Thread = pixel, 16 batch items (4 quads), all 4 o-channels.
// acc = 16 float4 (64 VGPR), weights single-buffered 5 float4 (20 VGPR),
// state 4 float4/chunk from LDS + DPP row-shift taps. launch_bounds(256,2):
// budget 256 -> allocator's consistent halving gives 128 arch VGPRs (R4
// empirical); true live ~115 fits -> no AGPR copies, no scratch.
// LDS: smv[c][y][x*4 + (q ^ ((x>>1)&3))] -- each 16-lane row covers all 8
// f4-start-banks -> ds_read_b128 at its 8-cycle floor. 64 KiB, 2 blocks/CU.
// Weight stream: runtime c/u loop + sched_barrier(0) before reload (the
// proven fence against scheduler load-hoisting). 400 KB/block-step from L2,
// now amortized over 2x the FMAs vs R9/R10.
__global__ __launch_bounds__(256, 2)
void reservoir_kernel(const float* __restrict__ X, const float4* __restrict__ Wt,
                      float* __restrict__ out, int batch) {
    __shared__ float4 smv[NC * CROW];   // 65536 B
    float* smf = reinterpret_cast<float*>(smv);

    const int tid = threadIdx.x;        // pixel index
    const int y = tid >> 4;
    const int x = tid & 15;
    const long itemBase = (long)blockIdx.x * BPB;

    const int sw = (x >> 1) & 3;        // quad-slot swizzle
    const int xb = x << 2;

    // ---- init: X (first 784 of 1024 slots) -> LDS ----
    for (int b = 0; b < BPB; ++b) {
        long item = itemBase + b;
        #pragma unroll
        for (int k = 0; k < 4; ++k) {
            int idx = tid + k * 256;
            float v = 0.f;
            if (idx < 784 && item < batch)
                v = __builtin_nontemporal_load(&X[item * 784 + idx]);
            int c = idx >> 8, rem = idx & 255, yy = rem >> 4, xx = rem & 15;
            int phys = (b >> 2) ^ ((xx >> 1) & 3);
            smf[(((c * NG + yy) << 6) + (xx << 2) + phys) * 4 + (b & 3)] = v;
        }
    }

    // ---- weights: single-buffered 5 x float4, chunk 0 preloaded ----
    const float4* Wp = Wt + tid;
    float4 w0 = Wp[0], w1 = Wp[256], w2 = Wp[512], w3 = Wp[768], w4 = Wp[1024];
    int wnext = 1280;    // f4 offset of next chunk (chunk k at k*1280)

    __syncthreads();

    // acc[o][q]: o = out channel, q = batch quad (items 4q..4q+3)
#define TAPQ(WV, T, Q) \
    fma4(WV.x, T, a0##Q); fma4(WV.y, T, a1##Q); \
    fma4(WV.z, T, a2##Q); fma4(WV.w, T, a3##Q);

#define QBLOCK(SQ, Q) { \
    TAPQ(w2, SQ, Q) \
    { const float4 tp = dpp4<0x111>(SQ); TAPQ(w1, tp, Q) } \
    { const float4 tp = dpp4<0x101>(SQ); TAPQ(w3, tp, Q) } \
    { const float4 tp = dpp4<0x112>(SQ); TAPQ(w0, tp, Q) } \
    { const float4 tp = dpp4<0x102>(SQ); TAPQ(w4, tp, Q) } }

    #pragma unroll 1
    for (int t = 0; t < TSTEPS; ++t) {
        float4 a00 = {0,0,0,0}, a01 = {0,0,0,0}, a02 = {0,0,0,0}, a03 = {0,0,0,0};
        float4 a10 = {0,0,0,0}, a11 = {0,0,0,0}, a12 = {0,0,0,0}, a13 = {0,0,0,0};
        float4 a20 = {0,0,0,0}, a21 = {0,0,0,0}, a22 = {0,0,0,0}, a23 = {0,0,0,0};
        float4 a30 = {0,0,0,0}, a31 = {0,0,0,0}, a32 = {0,0,0,0}, a33 = {0,0,0,0};

        #pragma unroll 1
        for (int c = 0; c < NC; ++c) {
            #pragma unroll 1
            for (int u = 0; u < 5; ++u) {
                int yy = y + u - 2;
                yy = yy < 0 ? 0 : (yy > 15 ? 15 : yy);   // OOB rows: w pre-zeroed
                const int rb = ((c * NG + yy) << 6) + xb;
                const float4 s0 = smv[rb + (0 ^ sw)];
                const float4 s1 = smv[rb + (1 ^ sw)];
                const float4 s2 = smv[rb + (2 ^ sw)];
                const float4 s3 = smv[rb + (3 ^ sw)];

                QBLOCK(s0, 0)
                QBLOCK(s1, 1)
                QBLOCK(s2, 2)
                QBLOCK(s3, 3)

                // reload same regs with the NEXT chunk (after all consumers)
                __builtin_amdgcn_sched_barrier(0);
                w0 = Wp[wnext];
                w1 = Wp[wnext + 256];
                w2 = Wp[wnext + 512];
                w3 = Wp[wnext + 768];
                w4 = Wp[wnext + 1024];
                wnext += 1280;
                if (wnext >= 25600) wnext = 0;   // chunk 19 -> chunk 0
            }
        }

        a00 = lrelu4(a00); a01 = lrelu4(a01); a02 = lrelu4(a02); a03 = lrelu4(a03);
        a10 = lrelu4(a10); a11 = lrelu4(a11); a12 = lrelu4(a12); a13 = lrelu4(a13);
        a20 = lrelu4(a20); a21 = lrelu4(a21); a22 = lrelu4(a22); a23 = lrelu4(a23);
        a30 = lrelu4(a30); a31 = lrelu4(a31); a32 = lrelu4(a32); a33 = lrelu4(a33);

        if (t < TSTEPS - 1) {
            __syncthreads();   // all reads of S[t] complete before overwrite
            const int pb = (y << 6) + xb;
            smv[(0 * NG << 6) + pb + (0 ^ sw)] = a00;
            smv[(0 * NG << 6) + pb + (1 ^ sw)] = a01;
            smv[(0 * NG << 6) + pb + (2 ^ sw)] = a02;
            smv[(0 * NG << 6) + pb + (3 ^ sw)] = a03;
            smv[(1 * NG << 6) + pb + (0 ^ sw)] = a10;
            smv[(1 * NG << 6) + pb + (1 ^ sw)] = a11;
            smv[(1 * NG << 6) + pb + (2 ^ sw)] = a12;
            smv[(1 * NG << 6) + pb + (3 ^ sw)] = a13;
            smv[(2 * NG << 6) + pb + (0 ^ sw)] = a20;
            smv[(2 * NG << 6) + pb + (1 ^ sw)] = a21;
            smv[(2 * NG << 6) + pb + (2 ^ sw)] = a22;
            smv[(2 * NG << 6) + pb + (3 ^ sw)] = a23;
            smv[(3 * NG << 6) + pb + (0 ^ sw)] = a30;
            smv[(3 * NG << 6) + pb + (1 ^ sw)] = a31;
            smv[(3 * NG << 6) + pb + (2 ^ sw)] = a32;
            smv[(3 * NG << 6) + pb + (3 ^ sw)] = a33;
            __syncthreads();   // writes visible before next read phase
        } else {
            // channel-mean: p[q] covers items 4q..4q+3
            float4 p0, p1, p2, p3;
            p0.x = (a00.x + a10.x + a20.x + a30.x) * 0.25f;
            p0.y = (a00.y + a10.y + a20.y + a30.y) * 0.25f;
            p0.z = (a00.z + a10.z + a20.z + a30.z) * 0.25f;
            p0.w = (a00.w + a10.w + a20.w + a30.w) * 0.25f;
            p1.x = (a01.x + a11.x + a21.x + a31.x) * 0.25f;
            p1.y = (a01.y + a11.y + a21.y + a31.y) * 0.25f;
            p1.z = (a01.z + a11.z + a21.z + a31.z) * 0.25f;
            p1.w = (a01.w + a11.w + a21.w + a31.w) * 0.25f;
            p2.x = (a02.x + a12.x + a22.x + a32.x) * 0.25f;
            p2.y = (a02.y + a12.y + a22.y + a32.y) * 0.25f;
            p2.z = (a02.z + a12.z + a22.z + a32.z) * 0.25f;
            p2.w = (a02.w + a12.w + a22.w + a32.w) * 0.25f;
            p3.x = (a03.x + a13.x + a23.x + a33.x) * 0.25f;
            p3.y = (a03.y + a13.y + a23.y + a33.y) * 0.25f;
            p3.z = (a03.z + a13.z + a23.z + a33.z) * 0.25f;
            p3.w = (a03.w + a13.w + a23.w + a33.w) * 0.25f;
            const long ob = itemBase * 256 + tid;
            if (itemBase + 0  < batch) __builtin_nontemporal_store(p0.x, &out[ob + 0  * 256]);
            if (itemBase + 1  < batch) __builtin_nontemporal_store(p0.y, &out[ob + 1  * 256]);
            if (itemBase + 2  < batch) __builtin_nontemporal_store(p0.z, &out[ob + 2  * 256]);
            if (itemBase + 3  < batch) __builtin_nontemporal_store(p0.w, &out[ob + 3  * 256]);
            if (itemBase + 4  < batch) __builtin_nontemporal_store(p1.x, &out[ob + 4  * 256]);
            if (itemBase + 5  < batch) __builtin_nontemporal_store(p1.y, &out[ob + 5  * 256]);
            if (itemBase + 6  < batch) __builtin_nontemporal_store(p1.z, &out[ob + 6  * 256]);
            if (itemBase + 7  < batch) __builtin_nontemporal_store(p1.w, &out[ob + 7  * 256]);
            if (itemBase + 8  < batch) __builtin_nontemporal_store(p2.x, &out[ob + 8  * 256]);
            if (itemBase + 9  < batch) __builtin_nontemporal_store(p2.y, &out[ob + 9  * 256]);
            if (itemBase + 10 < batch) __builtin_nontemporal_store(p2.z, &out[ob + 10 * 256]);
            if (itemBase + 11 < batch) __builtin_nontemporal_store(p2.w, &out[ob + 11 * 256]);
            if (itemBase + 12 < batch) __builtin_nontemporal_store(p3.x, &out[ob + 12 * 256]);
            if (itemBase + 13 < batch) __builtin_nontemporal_store(p3.y, &out[ob + 13 * 256]);
            if (itemBase + 14 < batch) __builtin_nontemporal_store(p3.z, &out[ob + 14 * 256]);
            if (itemBase + 15 < batch) __builtin_nontemporal_store(p3.w, &out[ob + 15 * 256]);
        }
    }
}

extern "C" void kernel_launch(void* const* d_in, const int* in_sizes, int n_in,
                              void* d_out, int out_size, void* d_ws, size_t ws_size,
                              hipStream_t stream) {
    const float* X = (const float*)d_in[0];
    const float* W = (const float*)d_in[1];
    float* out = (float*)d_out;
    const int batch = in_sizes[0] / 784;            // 8192
    const int blocks = (batch + BPB - 1) / BPB;     // 512

    wt_transpose<<<100, 256, 0, stream>>>(W, (float4*)d_ws);
    reservoir_kernel<<<blocks, 256, 0, stream>>>(
        X, (const float4*)d_ws, out, batch);
}